// Round 1
// baseline (1125.919 us; speedup 1.0000x reference)
//
#include <hip/hip_runtime.h>
#include <math.h>

// Problem constants (fixed shapes from setup_inputs)
#define Bn 32
#define TT 512
#define TM 2048
#define DD 512
#define MMp 80
#define NEGF (-1.0e9f)

// d_out layout: [h_expanded 32*2048*512][dur_loss 1][durations 32*512], all float32
constexpr size_t LOSS_OFF = (size_t)Bn * TM * DD;          // 33554432
constexpr size_t DUR_OFF  = LOSS_OFF + 1;                  // 33554433

// ---------------------------------------------------------------------------
// K0: build wTx[96][512]: rows 0..79 = w_proj^T, row 80 = b_proj, 81..95 = 0
// ---------------------------------------------------------------------------
__global__ __launch_bounds__(256) void k0_wtx(const float* __restrict__ w,
                                              const float* __restrict__ bias,
                                              float* __restrict__ wTx) {
    int m = blockIdx.x;
    for (int d = threadIdx.x; d < DD; d += 256) {
        float v = 0.f;
        if (m < 80) v = w[d * 80 + m];
        else if (m == 80) v = bias[d];
        wTx[m * DD + d] = v;
    }
}

// ---------------------------------------------------------------------------
// K1: hwX[b][m][i] = sum_d h_text[b][i][d] * wTx[m][d]   (m<96, row80 = h.b)
// Tiled fp32 GEMM: block = 64 rows x 96 cols, K-chunks of 64 staged in LDS.
// ---------------------------------------------------------------------------
__global__ __launch_bounds__(256) void k1_hw(const float* __restrict__ h_text,
                                             const float* __restrict__ wTx,
                                             float* __restrict__ hwX) {
    int bid = blockIdx.x;
    int b = bid >> 3;
    int i0 = (bid & 7) * 64;
    int t = threadIdx.x;
    int tr = t & 15, tc = t >> 4;
    __shared__ __align__(16) float Asub[64 * 68];
    __shared__ __align__(16) float Bsub[96 * 68];
    float acc[4][6];
#pragma unroll
    for (int a = 0; a < 4; ++a)
#pragma unroll
        for (int c = 0; c < 6; ++c) acc[a][c] = 0.f;

    for (int d0 = 0; d0 < DD; d0 += 64) {
        __syncthreads();
#pragma unroll
        for (int p = 0; p < 4; ++p) {
            int lin = p * 256 + t;              // 0..1023
            int r = lin >> 4, dq = lin & 15;
            *(float4*)&Asub[r * 68 + dq * 4] =
                *(const float4*)&h_text[((size_t)(b * TT + i0 + r)) * DD + d0 + dq * 4];
        }
#pragma unroll
        for (int p = 0; p < 6; ++p) {
            int lin = p * 256 + t;              // 0..1535
            int cc = lin >> 4, dq = lin & 15;
            *(float4*)&Bsub[cc * 68 + dq * 4] =
                *(const float4*)&wTx[(size_t)cc * DD + d0 + dq * 4];
        }
        __syncthreads();
#pragma unroll
        for (int dd = 0; dd < 16; ++dd) {
            float4 a[4], bb[6];
#pragma unroll
            for (int ri = 0; ri < 4; ++ri)
                a[ri] = *(const float4*)&Asub[(tr * 4 + ri) * 68 + dd * 4];
#pragma unroll
            for (int ci = 0; ci < 6; ++ci)
                bb[ci] = *(const float4*)&Bsub[(tc * 6 + ci) * 68 + dd * 4];
#pragma unroll
            for (int ri = 0; ri < 4; ++ri)
#pragma unroll
                for (int ci = 0; ci < 6; ++ci) {
                    acc[ri][ci] += a[ri].x * bb[ci].x;
                    acc[ri][ci] += a[ri].y * bb[ci].y;
                    acc[ri][ci] += a[ri].z * bb[ci].z;
                    acc[ri][ci] += a[ri].w * bb[ci].w;
                }
        }
    }
#pragma unroll
    for (int ri = 0; ri < 4; ++ri)
#pragma unroll
        for (int ci = 0; ci < 6; ++ci)
            hwX[((size_t)b * 96 + tc * 6 + ci) * DD + i0 + tr * 4 + ri] = acc[ri][ci];
}

// ---------------------------------------------------------------------------
// K2: attn + masked log_softmax over text axis, written transposed:
//   logpT[b][j][i] = (S - colmax) - log(sum exp(S - colmax)),  NEG if i>=tl
//   S[i][j] = hb[i] + sum_m hw[i][m]*mel[m][j]
// Block: one (b, 32-wide j tile), full i=512 column strip.
// ---------------------------------------------------------------------------
__global__ __launch_bounds__(256) void k2_attn(const float* __restrict__ hwX,
                                               const float* __restrict__ mel,
                                               const int* __restrict__ tlen,
                                               const int* __restrict__ mlen,
                                               float* __restrict__ logpT) {
    const int b = blockIdx.y;
    const int ml = mlen[b];
    const int j0 = blockIdx.x * 32;
    if (j0 >= ml) return;
    const int tl = tlen[b];
    const int tid = threadIdx.x;
    const int ig = tid >> 2;   // 64 i-groups, 8 rows each
    const int jg = tid & 3;    // 4 j-groups, 8 cols each

    __shared__ __align__(16) float hwS[16 * 512];
    __shared__ __align__(16) float melS[16 * 32];
    __shared__ float red[32 * 64];
    __shared__ float colmax[32];
    __shared__ float lsum[32];

    float acc[8][8];
#pragma unroll
    for (int a = 0; a < 8; ++a)
#pragma unroll
        for (int c = 0; c < 8; ++c) acc[a][c] = 0.f;

    for (int mc = 0; mc < 80; mc += 16) {
        __syncthreads();
#pragma unroll
        for (int p = 0; p < 8; ++p) {
            int lin = p * 256 + tid;            // 0..2047 float4s
            int mm = lin >> 7, iq = lin & 127;
            *(float4*)&hwS[mm * 512 + iq * 4] =
                *(const float4*)&hwX[((size_t)b * 96 + mc + mm) * DD + iq * 4];
        }
#pragma unroll
        for (int p = 0; p < 2; ++p) {
            int lin = p * 256 + tid;            // 0..511
            int mm = lin >> 5, jj = lin & 31;
            melS[lin] = mel[((size_t)b * 80 + mc + mm) * TM + j0 + jj];
        }
        __syncthreads();
#pragma unroll
        for (int mm = 0; mm < 16; ++mm) {
            float4 a0 = *(const float4*)&hwS[mm * 512 + ig * 8];
            float4 a1 = *(const float4*)&hwS[mm * 512 + ig * 8 + 4];
            float4 b0 = *(const float4*)&melS[mm * 32 + jg * 8];
            float4 b1 = *(const float4*)&melS[mm * 32 + jg * 8 + 4];
            float av[8] = {a0.x, a0.y, a0.z, a0.w, a1.x, a1.y, a1.z, a1.w};
            float bv[8] = {b0.x, b0.y, b0.z, b0.w, b1.x, b1.y, b1.z, b1.w};
#pragma unroll
            for (int ii = 0; ii < 8; ++ii)
#pragma unroll
                for (int jj = 0; jj < 8; ++jj) acc[ii][jj] += av[ii] * bv[jj];
        }
    }
    // add hb (row 80 of hwX), apply text mask
    float4 h0 = *(const float4*)&hwX[((size_t)b * 96 + 80) * DD + ig * 8];
    float4 h1 = *(const float4*)&hwX[((size_t)b * 96 + 80) * DD + ig * 8 + 4];
    float hb[8] = {h0.x, h0.y, h0.z, h0.w, h1.x, h1.y, h1.z, h1.w};
#pragma unroll
    for (int ii = 0; ii < 8; ++ii) {
        bool valid = (ig * 8 + ii) < tl;
#pragma unroll
        for (int jj = 0; jj < 8; ++jj)
            acc[ii][jj] = valid ? (acc[ii][jj] + hb[ii]) : NEGF;
    }
    __syncthreads();
    // column max over i
#pragma unroll
    for (int jj = 0; jj < 8; ++jj) {
        float m = acc[0][jj];
#pragma unroll
        for (int ii = 1; ii < 8; ++ii) m = fmaxf(m, acc[ii][jj]);
        red[(jg * 8 + jj) * 64 + ig] = m;
    }
    __syncthreads();
    if (tid < 32) {
        float m = red[tid * 64];
        for (int g = 1; g < 64; ++g) m = fmaxf(m, red[tid * 64 + g]);
        colmax[tid] = m;
    }
    __syncthreads();
#pragma unroll
    for (int jj = 0; jj < 8; ++jj) {
        float cm = colmax[jg * 8 + jj];
        float s = 0.f;
#pragma unroll
        for (int ii = 0; ii < 8; ++ii) s += expf(acc[ii][jj] - cm);
        red[(jg * 8 + jj) * 64 + ig] = s;
    }
    __syncthreads();
    if (tid < 32) {
        float s = 0.f;
        for (int g = 0; g < 64; ++g) s += red[tid * 64 + g];
        lsum[tid] = logf(s);
    }
    __syncthreads();
#pragma unroll
    for (int jj = 0; jj < 8; ++jj) {
        int j = j0 + jg * 8 + jj;
        if (j < ml) {
            float cm = colmax[jg * 8 + jj], ls = lsum[jg * 8 + jj];
            float o[8];
#pragma unroll
            for (int ii = 0; ii < 8; ++ii) {
                int i = ig * 8 + ii;
                o[ii] = (i < tl) ? ((acc[ii][jj] - cm) - ls) : NEGF;
            }
            float* dst = &logpT[((size_t)b * TM + j) * TT + ig * 8];
            *(float4*)dst = make_float4(o[0], o[1], o[2], o[3]);
            *(float4*)(dst + 4) = make_float4(o[4], o[5], o[6], o[7]);
        }
    }
}

// ---------------------------------------------------------------------------
// K3: MAS forward DP + backtrack + durations + cumsum + idxmap.
// One wave per batch. Lane l owns rows 8l..8l+7.
// Choices stored i-major as u32 bitmasks (gwords[b][jw][i], bit = j&31),
// accumulated in registers and flushed every 32 frames (coalesced).
// ---------------------------------------------------------------------------
__global__ __launch_bounds__(64) void k3_dp(const float* __restrict__ logpT,
                                            const int* __restrict__ tlen,
                                            const int* __restrict__ mlen,
                                            unsigned* __restrict__ gwords,
                                            int* __restrict__ idxmap,
                                            float* __restrict__ dOut) {
    const int b = blockIdx.x;
    const int lane = threadIdx.x;
    const int tl = tlen[b];
    const int ml = mlen[b];
    __shared__ int durs[TT];
#pragma unroll
    for (int k = 0; k < 8; ++k) durs[lane * 8 + k] = 0;

    const float4* colv = (const float4*)(logpT + (size_t)b * TM * TT);
    unsigned* gw = gwords + (size_t)b * 64 * TT;

    float q[8];
    unsigned accb[8];
#pragma unroll
    for (int k = 0; k < 8; ++k) { q[k] = NEGF; accb[k] = 0u; }
    if (lane == 0) q[0] = logpT[(size_t)b * TM * TT];   // logp[b][j=0][i=0]

    float4 bA[8], bB[8];
#pragma unroll
    for (int p = 0; p < 8; ++p) {
        int jj = 1 + p;
        if (jj < ml) { bA[p] = colv[jj * 128 + lane * 2]; bB[p] = colv[jj * 128 + lane * 2 + 1]; }
    }
    for (int jb = 1; jb < ml; jb += 8) {
#pragma unroll
        for (int p = 0; p < 8; ++p) {
            const int j = jb + p;
            if (j < ml) {
                float4 la = bA[p], lbv = bB[p];
                int jn = j + 8;
                if (jn < ml) { bA[p] = colv[jn * 128 + lane * 2]; bB[p] = colv[jn * 128 + lane * 2 + 1]; }
                float lp[8] = {la.x, la.y, la.z, la.w, lbv.x, lbv.y, lbv.z, lbv.w};
                float qm1 = __shfl_up(q[7], 1);
                float nb[8];
                nb[0] = (lane == 0) ? NEGF : qm1;
#pragma unroll
                for (int k = 1; k < 8; ++k) nb[k] = q[k - 1];
                const unsigned m32 = 1u << (j & 31);
#pragma unroll
                for (int k = 0; k < 8; ++k) {
                    if (nb[k] > q[k]) accb[k] |= m32;     // take_diag = q_shift > q
                    q[k] = lp[k] + fmaxf(q[k], nb[k]);
                }
                if ((j & 31) == 31) {
                    const int jw = j >> 5;
#pragma unroll
                    for (int k = 0; k < 8; ++k) { gw[jw * TT + lane * 8 + k] = accb[k]; accb[k] = 0u; }
                }
            }
        }
    }
    if (((ml - 1) & 31) != 31) {
        const int jw = (ml - 1) >> 5;
#pragma unroll
        for (int k = 0; k < 8; ++k) gw[jw * TT + lane * 8 + k] = accb[k];
    }
    __threadfence();
    __syncthreads();

    if (lane == 0) {
        volatile const unsigned* vgw = gw;    // bypass vL1 (write-through no-allocate)
        int i = tl - 1;
        int j = ml - 1;
        for (;;) {
            int jw = j >> 5;
            int r = j & 31;
            unsigned w = vgw[jw * TT + i];
            w &= (r == 31) ? 0xFFFFFFFFu : ((1u << (r + 1)) - 1u);
            while (w == 0u && jw > 0) { --jw; w = vgw[jw * TT + i]; }
            if (w == 0u) { durs[i] += j + 1; break; }
            int jp = (jw << 5) + (31 - __clz(w));   // largest set bit <= j
            durs[i] += j - jp + 1;
            --i;
            j = jp - 1;
        }
    }
    __syncthreads();

    // durations -> d_out (as float); exclusive cumsum -> idxmap scatter fill
    int d[8], pre[8];
    int run = 0;
#pragma unroll
    for (int k = 0; k < 8; ++k) { d[k] = durs[lane * 8 + k]; pre[k] = run; run += d[k]; }
    int v = run;
#pragma unroll
    for (int off = 1; off < 64; off <<= 1) {
        int n = __shfl_up(v, off);
        if (lane >= off) v += n;
    }
    int base = v - run;
#pragma unroll
    for (int k = 0; k < 8; ++k) {
        int i = lane * 8 + k;
        dOut[DUR_OFF + (size_t)b * TT + i] = (float)d[k];
        int st = base + pre[k];
        for (int t2 = 0; t2 < d[k]; ++t2) idxmap[b * TM + st + t2] = i;
    }
}

// ---------------------------------------------------------------------------
// K4: length-regulate expansion. One block per output row (b, j).
// ---------------------------------------------------------------------------
__global__ __launch_bounds__(128) void k4_expand(const float* __restrict__ h_text,
                                                 const int* __restrict__ idxmap,
                                                 const int* __restrict__ mlen,
                                                 float* __restrict__ dOut) {
    int bid = blockIdx.x;
    int b = bid >> 11;
    int j = bid & (TM - 1);
    int t = threadIdx.x;
    float4* orow = (float4*)dOut + (size_t)bid * 128;
    if (j < mlen[b]) {
        int i = idxmap[bid];
        const float4* hrow = (const float4*)h_text + ((size_t)(b * TT + i)) * 128;
        orow[t] = hrow[t];
    } else {
        orow[t] = make_float4(0.f, 0.f, 0.f, 0.f);
    }
}

// ---------------------------------------------------------------------------
// K5: masked sum-MSE duration loss (reads float durations already in d_out)
// ---------------------------------------------------------------------------
__global__ __launch_bounds__(256) void k5_loss(const float* __restrict__ pred,
                                               const int* __restrict__ tlen,
                                               float* __restrict__ dOut) {
    __shared__ float rs[256];
    __shared__ int rc[256];
    int t = threadIdx.x;
    float s = 0.f;
    int c = 0;
    for (int idx = t; idx < Bn * TT; idx += 256) {
        int b = idx >> 9, i = idx & 511;
        if (i < tlen[b]) {
            float dv = dOut[DUR_OFF + idx];
            float lg = logf(fmaxf(dv, 1.0f));
            float df = pred[idx] - lg;
            s += df * df;
            c += 1;
        }
    }
    rs[t] = s; rc[t] = c;
    __syncthreads();
    for (int off = 128; off > 0; off >>= 1) {
        if (t < off) { rs[t] += rs[t + off]; rc[t] += rc[t + off]; }
        __syncthreads();
    }
    if (t == 0) dOut[LOSS_OFF] = rs[0] / (float)rc[0];
}

// ---------------------------------------------------------------------------
extern "C" void kernel_launch(void* const* d_in, const int* in_sizes, int n_in,
                              void* d_out, int out_size, void* d_ws, size_t ws_size,
                              hipStream_t stream) {
    const float* h_text = (const float*)d_in[0];
    const float* mel    = (const float*)d_in[1];
    const int*   tlen   = (const int*)d_in[2];
    const int*   mlen   = (const int*)d_in[3];
    const float* w      = (const float*)d_in[4];
    const float* bias   = (const float*)d_in[5];
    const float* pred   = (const float*)d_in[6];
    float* out = (float*)d_out;

    // workspace carve-up (~145 MB)
    float*    logpT  = (float*)d_ws;                              // 32*2048*512 f32 (128 MB)
    float*    hwX    = logpT + (size_t)Bn * TM * TT;              // 32*96*512 f32
    float*    wTx    = hwX + (size_t)Bn * 96 * DD;                // 96*512 f32
    unsigned* gwords = (unsigned*)(wTx + 96 * DD);                // 32*64*512 u32 (4 MB)
    int*      idxmap = (int*)(gwords + (size_t)Bn * 64 * TT);     // 32*2048 i32

    k0_wtx<<<dim3(96), dim3(256), 0, stream>>>(w, bias, wTx);
    k1_hw<<<dim3(256), dim3(256), 0, stream>>>(h_text, wTx, hwX);
    k2_attn<<<dim3(64, 32), dim3(256), 0, stream>>>(hwX, mel, tlen, mlen, logpT);
    k3_dp<<<dim3(32), dim3(64), 0, stream>>>(logpT, tlen, mlen, gwords, idxmap, out);
    k4_expand<<<dim3(Bn * TM), dim3(128), 0, stream>>>(h_text, idxmap, mlen, out);
    k5_loss<<<dim3(1), dim3(256), 0, stream>>>(pred, tlen, out);
}

// Round 2
// 1062.680 us; speedup vs baseline: 1.0595x; 1.0595x over previous
//
#include <hip/hip_runtime.h>
#include <math.h>

// Problem constants (fixed shapes from setup_inputs)
#define Bn 32
#define TT 512
#define TM 2048
#define DD 512
#define MMp 80
#define NEGF (-1.0e9f)

// d_out layout: [h_expanded 32*2048*512][dur_loss 1][durations 32*512], all float32
constexpr size_t LOSS_OFF = (size_t)Bn * TM * DD;          // 33554432
constexpr size_t DUR_OFF  = LOSS_OFF + 1;                  // 33554433

// ---------------------------------------------------------------------------
// K0: build wTx[96][512]: rows 0..79 = w_proj^T, row 80 = b_proj, 81..95 = 0
// ---------------------------------------------------------------------------
__global__ __launch_bounds__(256) void k0_wtx(const float* __restrict__ w,
                                              const float* __restrict__ bias,
                                              float* __restrict__ wTx) {
    int m = blockIdx.x;
    for (int d = threadIdx.x; d < DD; d += 256) {
        float v = 0.f;
        if (m < 80) v = w[d * 80 + m];
        else if (m == 80) v = bias[d];
        wTx[m * DD + d] = v;
    }
}

// ---------------------------------------------------------------------------
// K1: hwX[b][m][i] = sum_d h_text[b][i][d] * wTx[m][d]   (m<96, row80 = h.b)
// ---------------------------------------------------------------------------
__global__ __launch_bounds__(256) void k1_hw(const float* __restrict__ h_text,
                                             const float* __restrict__ wTx,
                                             float* __restrict__ hwX) {
    int bid = blockIdx.x;
    int b = bid >> 3;
    int i0 = (bid & 7) * 64;
    int t = threadIdx.x;
    int tr = t & 15, tc = t >> 4;
    __shared__ __align__(16) float Asub[64 * 68];
    __shared__ __align__(16) float Bsub[96 * 68];
    float acc[4][6];
#pragma unroll
    for (int a = 0; a < 4; ++a)
#pragma unroll
        for (int c = 0; c < 6; ++c) acc[a][c] = 0.f;

    for (int d0 = 0; d0 < DD; d0 += 64) {
        __syncthreads();
#pragma unroll
        for (int p = 0; p < 4; ++p) {
            int lin = p * 256 + t;              // 0..1023
            int r = lin >> 4, dq = lin & 15;
            *(float4*)&Asub[r * 68 + dq * 4] =
                *(const float4*)&h_text[((size_t)(b * TT + i0 + r)) * DD + d0 + dq * 4];
        }
#pragma unroll
        for (int p = 0; p < 6; ++p) {
            int lin = p * 256 + t;              // 0..1535
            int cc = lin >> 4, dq = lin & 15;
            *(float4*)&Bsub[cc * 68 + dq * 4] =
                *(const float4*)&wTx[(size_t)cc * DD + d0 + dq * 4];
        }
        __syncthreads();
#pragma unroll
        for (int dd = 0; dd < 16; ++dd) {
            float4 a[4], bb[6];
#pragma unroll
            for (int ri = 0; ri < 4; ++ri)
                a[ri] = *(const float4*)&Asub[(tr * 4 + ri) * 68 + dd * 4];
#pragma unroll
            for (int ci = 0; ci < 6; ++ci)
                bb[ci] = *(const float4*)&Bsub[(tc * 6 + ci) * 68 + dd * 4];
#pragma unroll
            for (int ri = 0; ri < 4; ++ri)
#pragma unroll
                for (int ci = 0; ci < 6; ++ci) {
                    acc[ri][ci] += a[ri].x * bb[ci].x;
                    acc[ri][ci] += a[ri].y * bb[ci].y;
                    acc[ri][ci] += a[ri].z * bb[ci].z;
                    acc[ri][ci] += a[ri].w * bb[ci].w;
                }
        }
    }
#pragma unroll
    for (int ri = 0; ri < 4; ++ri)
#pragma unroll
        for (int ci = 0; ci < 6; ++ci)
            hwX[((size_t)b * 96 + tc * 6 + ci) * DD + i0 + tr * 4 + ri] = acc[ri][ci];
}

// ---------------------------------------------------------------------------
// K2: attn + masked log_softmax over text axis, written transposed:
//   logpT[b][j][i]
// ---------------------------------------------------------------------------
__global__ __launch_bounds__(256) void k2_attn(const float* __restrict__ hwX,
                                               const float* __restrict__ mel,
                                               const int* __restrict__ tlen,
                                               const int* __restrict__ mlen,
                                               float* __restrict__ logpT) {
    const int b = blockIdx.y;
    const int ml = mlen[b];
    const int j0 = blockIdx.x * 32;
    if (j0 >= ml) return;
    const int tl = tlen[b];
    const int tid = threadIdx.x;
    const int ig = tid >> 2;   // 64 i-groups, 8 rows each
    const int jg = tid & 3;    // 4 j-groups, 8 cols each

    __shared__ __align__(16) float hwS[16 * 512];
    __shared__ __align__(16) float melS[16 * 32];
    __shared__ float red[32 * 64];
    __shared__ float colmax[32];
    __shared__ float lsum[32];

    float acc[8][8];
#pragma unroll
    for (int a = 0; a < 8; ++a)
#pragma unroll
        for (int c = 0; c < 8; ++c) acc[a][c] = 0.f;

    for (int mc = 0; mc < 80; mc += 16) {
        __syncthreads();
#pragma unroll
        for (int p = 0; p < 8; ++p) {
            int lin = p * 256 + tid;            // 0..2047 float4s
            int mm = lin >> 7, iq = lin & 127;
            *(float4*)&hwS[mm * 512 + iq * 4] =
                *(const float4*)&hwX[((size_t)b * 96 + mc + mm) * DD + iq * 4];
        }
#pragma unroll
        for (int p = 0; p < 2; ++p) {
            int lin = p * 256 + tid;            // 0..511
            int mm = lin >> 5, jj = lin & 31;
            melS[lin] = mel[((size_t)b * 80 + mc + mm) * TM + j0 + jj];
        }
        __syncthreads();
#pragma unroll
        for (int mm = 0; mm < 16; ++mm) {
            float4 a0 = *(const float4*)&hwS[mm * 512 + ig * 8];
            float4 a1 = *(const float4*)&hwS[mm * 512 + ig * 8 + 4];
            float4 b0 = *(const float4*)&melS[mm * 32 + jg * 8];
            float4 b1 = *(const float4*)&melS[mm * 32 + jg * 8 + 4];
            float av[8] = {a0.x, a0.y, a0.z, a0.w, a1.x, a1.y, a1.z, a1.w};
            float bv[8] = {b0.x, b0.y, b0.z, b0.w, b1.x, b1.y, b1.z, b1.w};
#pragma unroll
            for (int ii = 0; ii < 8; ++ii)
#pragma unroll
                for (int jj = 0; jj < 8; ++jj) acc[ii][jj] += av[ii] * bv[jj];
        }
    }
    float4 h0 = *(const float4*)&hwX[((size_t)b * 96 + 80) * DD + ig * 8];
    float4 h1 = *(const float4*)&hwX[((size_t)b * 96 + 80) * DD + ig * 8 + 4];
    float hb[8] = {h0.x, h0.y, h0.z, h0.w, h1.x, h1.y, h1.z, h1.w};
#pragma unroll
    for (int ii = 0; ii < 8; ++ii) {
        bool valid = (ig * 8 + ii) < tl;
#pragma unroll
        for (int jj = 0; jj < 8; ++jj)
            acc[ii][jj] = valid ? (acc[ii][jj] + hb[ii]) : NEGF;
    }
    __syncthreads();
#pragma unroll
    for (int jj = 0; jj < 8; ++jj) {
        float m = acc[0][jj];
#pragma unroll
        for (int ii = 1; ii < 8; ++ii) m = fmaxf(m, acc[ii][jj]);
        red[(jg * 8 + jj) * 64 + ig] = m;
    }
    __syncthreads();
    if (tid < 32) {
        float m = red[tid * 64];
        for (int g = 1; g < 64; ++g) m = fmaxf(m, red[tid * 64 + g]);
        colmax[tid] = m;
    }
    __syncthreads();
#pragma unroll
    for (int jj = 0; jj < 8; ++jj) {
        float cm = colmax[jg * 8 + jj];
        float s = 0.f;
#pragma unroll
        for (int ii = 0; ii < 8; ++ii) s += expf(acc[ii][jj] - cm);
        red[(jg * 8 + jj) * 64 + ig] = s;
    }
    __syncthreads();
    if (tid < 32) {
        float s = 0.f;
        for (int g = 0; g < 64; ++g) s += red[tid * 64 + g];
        lsum[tid] = logf(s);
    }
    __syncthreads();
#pragma unroll
    for (int jj = 0; jj < 8; ++jj) {
        int j = j0 + jg * 8 + jj;
        if (j < ml) {
            float cm = colmax[jg * 8 + jj], ls = lsum[jg * 8 + jj];
            float o[8];
#pragma unroll
            for (int ii = 0; ii < 8; ++ii) {
                int i = ig * 8 + ii;
                o[ii] = (i < tl) ? ((acc[ii][jj] - cm) - ls) : NEGF;
            }
            float* dst = &logpT[((size_t)b * TM + j) * TT + ig * 8];
            *(float4*)dst = make_float4(o[0], o[1], o[2], o[3]);
            *(float4*)(dst + 4) = make_float4(o[4], o[5], o[6], o[7]);
        }
    }
}

// ---------------------------------------------------------------------------
// K3: MAS forward DP (branch-free, fixed 2048 steps, 16-deep register
// prefetch ring) + wave-parallel backtrack + durations + cumsum + idxmap.
// One wave per batch; lane l owns rows 8l..8l+7.
// Choice bits: gwords layout [b][i][jw] (row-major) so one row = 64 words =
// one coalesced 256B wave load at backtrack time.
// Bits for j >= ml are garbage but provably never read (top word always
// masked to bit (ml-1)&31; lower words only hold j' < ml bits).
// ---------------------------------------------------------------------------
__global__ __launch_bounds__(64) void k3_dp(const float* __restrict__ logpT,
                                            const int* __restrict__ tlen,
                                            const int* __restrict__ mlen,
                                            unsigned* __restrict__ gwords,
                                            int* __restrict__ idxmap,
                                            float* __restrict__ dOut) {
    const int b = blockIdx.x;
    const int lane = threadIdx.x;
    const int tl = tlen[b];
    const int ml = mlen[b];
    __shared__ int durs[TT];
#pragma unroll
    for (int k = 0; k < 8; ++k) durs[lane * 8 + k] = 0;

    const float* colbase = logpT + (size_t)b * TM * TT;
    const float4* pA = (const float4*)colbase + lane * 2;
    unsigned* gwb = gwords + (size_t)b * TT * 64;

    float q[8];
    unsigned accb[8];
#pragma unroll
    for (int k = 0; k < 8; ++k) { q[k] = NEGF; accb[k] = 0u; }
    if (lane == 0) q[0] = colbase[0];          // logp[b][j=0][i=0]

    // ---- forward DP: columns 1..2048 (step 2048 is a clamped dummy) ----
    float4 rA[16], rB[16];
#pragma unroll
    for (int p = 0; p < 16; ++p) {
        rA[p] = pA[(size_t)(1 + p) * 128];
        rB[p] = pA[(size_t)(1 + p) * 128 + 1];
    }
    unsigned* gp = gwb + lane * 8 * 64;        // flush cursor (word 0)

    for (int jb = 1; jb < TM; jb += 32) {      // jb = 1,33,...,2017 (64 iters)
#pragma unroll
        for (int p = 0; p < 32; ++p) {
            const int slot = p & 15;
            float4 la = rA[slot], lb = rB[slot];
            int c = jb + p + 16;
            c = (c > TM - 1) ? (TM - 1) : c;   // clamped tail prefetch
            rA[slot] = pA[(size_t)c * 128];
            rB[slot] = pA[(size_t)c * 128 + 1];
            float lp[8] = {la.x, la.y, la.z, la.w, lb.x, lb.y, lb.z, lb.w};
            float qm1 = __shfl_up(q[7], 1);
            float nb[8];
            nb[0] = (lane == 0) ? NEGF : qm1;
#pragma unroll
            for (int k = 1; k < 8; ++k) nb[k] = q[k - 1];
            const unsigned m32 = 1u << ((p + 1) & 31);   // compile-time const
#pragma unroll
            for (int k = 0; k < 8; ++k) {
                if (nb[k] > q[k]) accb[k] |= m32;        // take_diag = q_shift > q
                q[k] = lp[k] + fmaxf(q[k], nb[k]);
            }
            if (((p + 1) & 31) == 31) {        // p == 30: word complete
#pragma unroll
                for (int k = 0; k < 8; ++k) { gp[k * 64] = accb[k]; accb[k] = 0u; }
                gp += 1;
            }
        }
    }
    __threadfence();
    __syncthreads();

    // ---- wave-parallel backtrack: lane = word index within a row ----
    {
        int i = tl - 1;
        int j = ml - 1;
        unsigned r0, r1, r2, r3, r4, r5, r6, r7;   // 8-deep row shift register
        {
            int a0 = tl - 1, a1 = tl - 2, a2 = tl - 3, a3 = tl - 4;
            int a4 = tl - 5, a5 = tl - 6, a6 = tl - 7, a7 = tl - 8;
            a1 = a1 < 0 ? 0 : a1; a2 = a2 < 0 ? 0 : a2; a3 = a3 < 0 ? 0 : a3;
            a4 = a4 < 0 ? 0 : a4; a5 = a5 < 0 ? 0 : a5; a6 = a6 < 0 ? 0 : a6;
            a7 = a7 < 0 ? 0 : a7;
            r0 = gwb[a0 * 64 + lane]; r1 = gwb[a1 * 64 + lane];
            r2 = gwb[a2 * 64 + lane]; r3 = gwb[a3 * 64 + lane];
            r4 = gwb[a4 * 64 + lane]; r5 = gwb[a5 * 64 + lane];
            r6 = gwb[a6 * 64 + lane]; r7 = gwb[a7 * 64 + lane];
        }
        int nf = tl - 9;
        int guard = TT + 2;
        while (guard-- > 0) {
            unsigned w = r0;
            r0 = r1; r1 = r2; r2 = r3; r3 = r4; r4 = r5; r5 = r6; r6 = r7;
            {
                int rf = (nf < 0) ? 0 : nf;
                r7 = gwb[rf * 64 + lane];
                --nf;
            }
            int jw = j >> 5, rr = j & 31;
            unsigned topmask = (rr == 31) ? 0xFFFFFFFFu : ((1u << (rr + 1)) - 1u);
            unsigned wm = (lane < jw) ? w : ((lane == jw) ? (w & topmask) : 0u);
            unsigned long long bal = __ballot(wm != 0u);
            if (bal == 0ull) {                 // no transition: row i covers 0..j
                if (lane == 0) durs[i] = j + 1;
                break;
            }
            int hl = 63 - __clzll(bal);        // highest lane (word) with a bit
            unsigned whl = (unsigned)__builtin_amdgcn_readlane((int)wm, hl);
            int jp = (hl << 5) + (31 - __clz(whl));   // largest set bit <= j
            if (lane == 0) durs[i] = j - jp + 1;
            j = jp - 1;
            if (--i < 0) break;
        }
    }
    __syncthreads();

    // ---- durations -> d_out; exclusive cumsum -> idxmap scatter fill ----
    int d[8], pre[8];
    int run = 0;
#pragma unroll
    for (int k = 0; k < 8; ++k) { d[k] = durs[lane * 8 + k]; pre[k] = run; run += d[k]; }
    int v = run;
#pragma unroll
    for (int off = 1; off < 64; off <<= 1) {
        int n = __shfl_up(v, off);
        if (lane >= off) v += n;
    }
    int base = v - run;
#pragma unroll
    for (int k = 0; k < 8; ++k) {
        int i = lane * 8 + k;
        dOut[DUR_OFF + (size_t)b * TT + i] = (float)d[k];
        int st = base + pre[k];
        for (int t2 = 0; t2 < d[k]; ++t2) idxmap[b * TM + st + t2] = i;
    }
}

// ---------------------------------------------------------------------------
// K4: length-regulate expansion. One block per output row (b, j).
// ---------------------------------------------------------------------------
__global__ __launch_bounds__(128) void k4_expand(const float* __restrict__ h_text,
                                                 const int* __restrict__ idxmap,
                                                 const int* __restrict__ mlen,
                                                 float* __restrict__ dOut) {
    int bid = blockIdx.x;
    int b = bid >> 11;
    int j = bid & (TM - 1);
    int t = threadIdx.x;
    float4* orow = (float4*)dOut + (size_t)bid * 128;
    if (j < mlen[b]) {
        int i = idxmap[bid];
        const float4* hrow = (const float4*)h_text + ((size_t)(b * TT + i)) * 128;
        orow[t] = hrow[t];
    } else {
        orow[t] = make_float4(0.f, 0.f, 0.f, 0.f);
    }
}

// ---------------------------------------------------------------------------
// K5: masked sum-MSE duration loss
// ---------------------------------------------------------------------------
__global__ __launch_bounds__(256) void k5_loss(const float* __restrict__ pred,
                                               const int* __restrict__ tlen,
                                               float* __restrict__ dOut) {
    __shared__ float rs[256];
    __shared__ int rc[256];
    int t = threadIdx.x;
    float s = 0.f;
    int c = 0;
    for (int idx = t; idx < Bn * TT; idx += 256) {
        int b = idx >> 9, i = idx & 511;
        if (i < tlen[b]) {
            float dv = dOut[DUR_OFF + idx];
            float lg = logf(fmaxf(dv, 1.0f));
            float df = pred[idx] - lg;
            s += df * df;
            c += 1;
        }
    }
    rs[t] = s; rc[t] = c;
    __syncthreads();
    for (int off = 128; off > 0; off >>= 1) {
        if (t < off) { rs[t] += rs[t + off]; rc[t] += rc[t + off]; }
        __syncthreads();
    }
    if (t == 0) dOut[LOSS_OFF] = rs[0] / (float)rc[0];
}

// ---------------------------------------------------------------------------
extern "C" void kernel_launch(void* const* d_in, const int* in_sizes, int n_in,
                              void* d_out, int out_size, void* d_ws, size_t ws_size,
                              hipStream_t stream) {
    const float* h_text = (const float*)d_in[0];
    const float* mel    = (const float*)d_in[1];
    const int*   tlen   = (const int*)d_in[2];
    const int*   mlen   = (const int*)d_in[3];
    const float* w      = (const float*)d_in[4];
    const float* bias   = (const float*)d_in[5];
    const float* pred   = (const float*)d_in[6];
    float* out = (float*)d_out;

    // workspace carve-up (~138.5 MB)
    float*    logpT  = (float*)d_ws;                              // 32*2048*512 f32 (128 MB)
    float*    hwX    = logpT + (size_t)Bn * TM * TT;              // 32*96*512 f32
    float*    wTx    = hwX + (size_t)Bn * 96 * DD;                // 96*512 f32
    unsigned* gwords = (unsigned*)(wTx + 96 * DD);                // 32*512*64 u32 (4 MB)
    int*      idxmap = (int*)(gwords + (size_t)Bn * TT * 64);     // 32*2048 i32

    k0_wtx<<<dim3(96), dim3(256), 0, stream>>>(w, bias, wTx);
    k1_hw<<<dim3(256), dim3(256), 0, stream>>>(h_text, wTx, hwX);
    k2_attn<<<dim3(64, 32), dim3(256), 0, stream>>>(hwX, mel, tlen, mlen, logpT);
    k3_dp<<<dim3(32), dim3(64), 0, stream>>>(logpT, tlen, mlen, gwords, idxmap, out);
    k4_expand<<<dim3(Bn * TM), dim3(128), 0, stream>>>(h_text, idxmap, mlen, out);
    k5_loss<<<dim3(1), dim3(256), 0, stream>>>(pred, tlen, out);
}

// Round 3
// 936.187 us; speedup vs baseline: 1.2027x; 1.1351x over previous
//
#include <hip/hip_runtime.h>
#include <math.h>

// Problem constants (fixed shapes from setup_inputs)
#define Bn 32
#define TT 512
#define TM 2048
#define DD 512
#define MMp 80
#define NEGF (-1.0e9f)

// d_out layout: [h_expanded 32*2048*512][dur_loss 1][durations 32*512], all float32
constexpr size_t LOSS_OFF = (size_t)Bn * TM * DD;          // 33554432
constexpr size_t DUR_OFF  = LOSS_OFF + 1;                  // 33554433

// ---------------------------------------------------------------------------
// K0: build wTx[96][512]: rows 0..79 = w_proj^T, row 80 = b_proj, 81..95 = 0
// ---------------------------------------------------------------------------
__global__ __launch_bounds__(256) void k0_wtx(const float* __restrict__ w,
                                              const float* __restrict__ bias,
                                              float* __restrict__ wTx) {
    int m = blockIdx.x;
    for (int d = threadIdx.x; d < DD; d += 256) {
        float v = 0.f;
        if (m < 80) v = w[d * 80 + m];
        else if (m == 80) v = bias[d];
        wTx[m * DD + d] = v;
    }
}

// ---------------------------------------------------------------------------
// K1: hwX[b][m][i] = sum_d h_text[b][i][d] * wTx[m][d]   (m<96, row80 = h.b)
// ---------------------------------------------------------------------------
__global__ __launch_bounds__(256) void k1_hw(const float* __restrict__ h_text,
                                             const float* __restrict__ wTx,
                                             float* __restrict__ hwX) {
    int bid = blockIdx.x;
    int b = bid >> 3;
    int i0 = (bid & 7) * 64;
    int t = threadIdx.x;
    int tr = t & 15, tc = t >> 4;
    __shared__ __align__(16) float Asub[64 * 68];
    __shared__ __align__(16) float Bsub[96 * 68];
    float acc[4][6];
#pragma unroll
    for (int a = 0; a < 4; ++a)
#pragma unroll
        for (int c = 0; c < 6; ++c) acc[a][c] = 0.f;

    for (int d0 = 0; d0 < DD; d0 += 64) {
        __syncthreads();
#pragma unroll
        for (int p = 0; p < 4; ++p) {
            int lin = p * 256 + t;              // 0..1023
            int r = lin >> 4, dq = lin & 15;
            *(float4*)&Asub[r * 68 + dq * 4] =
                *(const float4*)&h_text[((size_t)(b * TT + i0 + r)) * DD + d0 + dq * 4];
        }
#pragma unroll
        for (int p = 0; p < 6; ++p) {
            int lin = p * 256 + t;              // 0..1535
            int cc = lin >> 4, dq = lin & 15;
            *(float4*)&Bsub[cc * 68 + dq * 4] =
                *(const float4*)&wTx[(size_t)cc * DD + d0 + dq * 4];
        }
        __syncthreads();
#pragma unroll
        for (int dd = 0; dd < 16; ++dd) {
            float4 a[4], bb[6];
#pragma unroll
            for (int ri = 0; ri < 4; ++ri)
                a[ri] = *(const float4*)&Asub[(tr * 4 + ri) * 68 + dd * 4];
#pragma unroll
            for (int ci = 0; ci < 6; ++ci)
                bb[ci] = *(const float4*)&Bsub[(tc * 6 + ci) * 68 + dd * 4];
#pragma unroll
            for (int ri = 0; ri < 4; ++ri)
#pragma unroll
                for (int ci = 0; ci < 6; ++ci) {
                    acc[ri][ci] += a[ri].x * bb[ci].x;
                    acc[ri][ci] += a[ri].y * bb[ci].y;
                    acc[ri][ci] += a[ri].z * bb[ci].z;
                    acc[ri][ci] += a[ri].w * bb[ci].w;
                }
        }
    }
#pragma unroll
    for (int ri = 0; ri < 4; ++ri)
#pragma unroll
        for (int ci = 0; ci < 6; ++ci)
            hwX[((size_t)b * 96 + tc * 6 + ci) * DD + i0 + tr * 4 + ri] = acc[ri][ci];
}

// ---------------------------------------------------------------------------
// K2: attn + masked log_softmax over text axis, written transposed:
//   logpT[b][j][i]
// ---------------------------------------------------------------------------
__global__ __launch_bounds__(256) void k2_attn(const float* __restrict__ hwX,
                                               const float* __restrict__ mel,
                                               const int* __restrict__ tlen,
                                               const int* __restrict__ mlen,
                                               float* __restrict__ logpT) {
    const int b = blockIdx.y;
    const int ml = mlen[b];
    const int j0 = blockIdx.x * 32;
    if (j0 >= ml) return;
    const int tl = tlen[b];
    const int tid = threadIdx.x;
    const int ig = tid >> 2;   // 64 i-groups, 8 rows each
    const int jg = tid & 3;    // 4 j-groups, 8 cols each

    __shared__ __align__(16) float hwS[16 * 512];
    __shared__ __align__(16) float melS[16 * 32];
    __shared__ float red[32 * 64];
    __shared__ float colmax[32];
    __shared__ float lsum[32];

    float acc[8][8];
#pragma unroll
    for (int a = 0; a < 8; ++a)
#pragma unroll
        for (int c = 0; c < 8; ++c) acc[a][c] = 0.f;

    for (int mc = 0; mc < 80; mc += 16) {
        __syncthreads();
#pragma unroll
        for (int p = 0; p < 8; ++p) {
            int lin = p * 256 + tid;            // 0..2047 float4s
            int mm = lin >> 7, iq = lin & 127;
            *(float4*)&hwS[mm * 512 + iq * 4] =
                *(const float4*)&hwX[((size_t)b * 96 + mc + mm) * DD + iq * 4];
        }
#pragma unroll
        for (int p = 0; p < 2; ++p) {
            int lin = p * 256 + tid;            // 0..511
            int mm = lin >> 5, jj = lin & 31;
            melS[lin] = mel[((size_t)b * 80 + mc + mm) * TM + j0 + jj];
        }
        __syncthreads();
#pragma unroll
        for (int mm = 0; mm < 16; ++mm) {
            float4 a0 = *(const float4*)&hwS[mm * 512 + ig * 8];
            float4 a1 = *(const float4*)&hwS[mm * 512 + ig * 8 + 4];
            float4 b0 = *(const float4*)&melS[mm * 32 + jg * 8];
            float4 b1 = *(const float4*)&melS[mm * 32 + jg * 8 + 4];
            float av[8] = {a0.x, a0.y, a0.z, a0.w, a1.x, a1.y, a1.z, a1.w};
            float bv[8] = {b0.x, b0.y, b0.z, b0.w, b1.x, b1.y, b1.z, b1.w};
#pragma unroll
            for (int ii = 0; ii < 8; ++ii)
#pragma unroll
                for (int jj = 0; jj < 8; ++jj) acc[ii][jj] += av[ii] * bv[jj];
        }
    }
    float4 h0 = *(const float4*)&hwX[((size_t)b * 96 + 80) * DD + ig * 8];
    float4 h1 = *(const float4*)&hwX[((size_t)b * 96 + 80) * DD + ig * 8 + 4];
    float hb[8] = {h0.x, h0.y, h0.z, h0.w, h1.x, h1.y, h1.z, h1.w};
#pragma unroll
    for (int ii = 0; ii < 8; ++ii) {
        bool valid = (ig * 8 + ii) < tl;
#pragma unroll
        for (int jj = 0; jj < 8; ++jj)
            acc[ii][jj] = valid ? (acc[ii][jj] + hb[ii]) : NEGF;
    }
    __syncthreads();
#pragma unroll
    for (int jj = 0; jj < 8; ++jj) {
        float m = acc[0][jj];
#pragma unroll
        for (int ii = 1; ii < 8; ++ii) m = fmaxf(m, acc[ii][jj]);
        red[(jg * 8 + jj) * 64 + ig] = m;
    }
    __syncthreads();
    if (tid < 32) {
        float m = red[tid * 64];
        for (int g = 1; g < 64; ++g) m = fmaxf(m, red[tid * 64 + g]);
        colmax[tid] = m;
    }
    __syncthreads();
#pragma unroll
    for (int jj = 0; jj < 8; ++jj) {
        float cm = colmax[jg * 8 + jj];
        float s = 0.f;
#pragma unroll
        for (int ii = 0; ii < 8; ++ii) s += expf(acc[ii][jj] - cm);
        red[(jg * 8 + jj) * 64 + ig] = s;
    }
    __syncthreads();
    if (tid < 32) {
        float s = 0.f;
        for (int g = 0; g < 64; ++g) s += red[tid * 64 + g];
        lsum[tid] = logf(s);
    }
    __syncthreads();
#pragma unroll
    for (int jj = 0; jj < 8; ++jj) {
        int j = j0 + jg * 8 + jj;
        if (j < ml) {
            float cm = colmax[jg * 8 + jj], ls = lsum[jg * 8 + jj];
            float o[8];
#pragma unroll
            for (int ii = 0; ii < 8; ++ii) {
                int i = ig * 8 + ii;
                o[ii] = (i < tl) ? ((acc[ii][jj] - cm) - ls) : NEGF;
            }
            float* dst = &logpT[((size_t)b * TM + j) * TT + ig * 8];
            *(float4*)dst = make_float4(o[0], o[1], o[2], o[3]);
            *(float4*)(dst + 4) = make_float4(o[4], o[5], o[6], o[7]);
        }
    }
}

// ---------------------------------------------------------------------------
// K3: MAS forward DP via double-buffered global_load_lds pipeline (fire-and-
// forget LDS-DMA: zero VGPR cost, compiler cannot collapse it like the r2
// register ring) + wave-parallel backtrack + durations + cumsum + idxmap.
// One wave per batch; lane l owns rows 8l..8l+7.
// Batch = 15 columns (2 KB each); issue batch n+1 (30 DMA ops), process batch
// n from LDS (2-deep ds_read register prefetch), drain vmcnt(0), swap.
// Choice bits: gwords layout [b][i][jw]; bits for j >= ml are garbage but
// provably never read (top word masked at (ml-1)&31; lower words < ml).
// ---------------------------------------------------------------------------
#define BCOLS 15
#define NBATCH 137   // ceil(2047/15); steps j = 1..2055, cols clamped to 2047

__device__ __forceinline__ void lds_dma16(const float* g, float* l) {
    __builtin_amdgcn_global_load_lds((const __attribute__((address_space(1))) void*)g,
                                     (__attribute__((address_space(3))) void*)l,
                                     16, 0, 0);
}
#define WAITALL asm volatile("s_waitcnt vmcnt(0)" ::: "memory")

__global__ __launch_bounds__(64) void k3_dp(const float* __restrict__ logpT,
                                            const int* __restrict__ tlen,
                                            const int* __restrict__ mlen,
                                            unsigned* __restrict__ gwords,
                                            int* __restrict__ idxmap,
                                            float* __restrict__ dOut) {
    const int b = blockIdx.x;
    const int lane = threadIdx.x;
    const int tl = tlen[b];
    const int ml = mlen[b];
    __shared__ __align__(16) float ring0[BCOLS * 512];
    __shared__ __align__(16) float ring1[BCOLS * 512];
    __shared__ int durs[TT];
#pragma unroll
    for (int k = 0; k < 8; ++k) durs[lane * 8 + k] = 0;

    const float* colbase = logpT + (size_t)b * TM * TT;
    unsigned* gwb = gwords + (size_t)b * TT * 64;

    float q[8];
    unsigned accb[8];
#pragma unroll
    for (int k = 0; k < 8; ++k) { q[k] = NEGF; accb[k] = 0u; }
    if (lane == 0) q[0] = colbase[0];          // logp[b][j=0][i=0]

    // ---- prologue: issue batch 0 (columns 1..15) into ring0 ----
    {
        const float* g0 = colbase + (size_t)512 + lane * 4;   // col 1, lane's 16B
#pragma unroll
        for (int p = 0; p < BCOLS; ++p) {
            lds_dma16(g0 + p * 512,       &ring0[p * 512]);
            lds_dma16(g0 + p * 512 + 256, &ring0[p * 512 + 256]);
        }
    }
    WAITALL;

    unsigned* gp = gwb + lane * 8 * 64;        // flush cursor (word 0)
    int jj = 1;
    for (int n = 0; n < NBATCH; ++n) {
        float* bufc = (n & 1) ? ring1 : ring0;     // current
        float* bufn = (n & 1) ? ring0 : ring1;     // next
        // ---- issue batch n+1 (fire-and-forget) ----
        if (n + 1 < NBATCH) {
            const int jb = 1 + (n + 1) * BCOLS;
#pragma unroll
            for (int p = 0; p < BCOLS; ++p) {
                int c = jb + p;
                c = (c > TM - 1) ? (TM - 1) : c;   // clamped dummy tail
                const float* g = colbase + (size_t)c * 512 + lane * 4;
                lds_dma16(g,       &bufn[p * 512]);
                lds_dma16(g + 256, &bufn[p * 512 + 256]);
            }
        }
        // ---- process batch n from LDS (2-deep register prefetch) ----
        float4 s0a = *(const float4*)&bufc[0 * 512 + lane * 8];
        float4 s0b = *(const float4*)&bufc[0 * 512 + lane * 8 + 4];
        float4 s1a = *(const float4*)&bufc[1 * 512 + lane * 8];
        float4 s1b = *(const float4*)&bufc[1 * 512 + lane * 8 + 4];
#pragma unroll
        for (int p = 0; p < BCOLS; ++p) {
            float4 la = (p & 1) ? s1a : s0a;
            float4 lb = (p & 1) ? s1b : s0b;
            if (p + 2 < BCOLS) {
                if (p & 1) {
                    s1a = *(const float4*)&bufc[(p + 2) * 512 + lane * 8];
                    s1b = *(const float4*)&bufc[(p + 2) * 512 + lane * 8 + 4];
                } else {
                    s0a = *(const float4*)&bufc[(p + 2) * 512 + lane * 8];
                    s0b = *(const float4*)&bufc[(p + 2) * 512 + lane * 8 + 4];
                }
            }
            float lp[8] = {la.x, la.y, la.z, la.w, lb.x, lb.y, lb.z, lb.w};
            float qm1 = __shfl_up(q[7], 1);
            float nb[8];
            nb[0] = (lane == 0) ? NEGF : qm1;
#pragma unroll
            for (int k = 1; k < 8; ++k) nb[k] = q[k - 1];
            const unsigned m32 = 1u << (jj & 31);
#pragma unroll
            for (int k = 0; k < 8; ++k) {
                if (nb[k] > q[k]) accb[k] |= m32;        // take_diag = q_shift > q
                q[k] = lp[k] + fmaxf(q[k], nb[k]);
            }
            if ((jj & 31) == 31) {             // word complete (uniform branch)
#pragma unroll
                for (int k = 0; k < 8; ++k) { gp[k * 64] = accb[k]; accb[k] = 0u; }
                gp += 1;
            }
            ++jj;
        }
        WAITALL;                               // batch n+1 resident before swap
    }
    __threadfence();
    __syncthreads();

    // ---- wave-parallel backtrack: lane = word index within a row ----
    {
        int i = tl - 1;
        int j = ml - 1;
        unsigned r0, r1, r2, r3, r4, r5, r6, r7;   // 8-deep row shift register
        {
            int a0 = tl - 1, a1 = tl - 2, a2 = tl - 3, a3 = tl - 4;
            int a4 = tl - 5, a5 = tl - 6, a6 = tl - 7, a7 = tl - 8;
            a1 = a1 < 0 ? 0 : a1; a2 = a2 < 0 ? 0 : a2; a3 = a3 < 0 ? 0 : a3;
            a4 = a4 < 0 ? 0 : a4; a5 = a5 < 0 ? 0 : a5; a6 = a6 < 0 ? 0 : a6;
            a7 = a7 < 0 ? 0 : a7;
            r0 = gwb[a0 * 64 + lane]; r1 = gwb[a1 * 64 + lane];
            r2 = gwb[a2 * 64 + lane]; r3 = gwb[a3 * 64 + lane];
            r4 = gwb[a4 * 64 + lane]; r5 = gwb[a5 * 64 + lane];
            r6 = gwb[a6 * 64 + lane]; r7 = gwb[a7 * 64 + lane];
        }
        int nf = tl - 9;
        int guard = TT + 2;
        while (guard-- > 0) {
            unsigned w = r0;
            r0 = r1; r1 = r2; r2 = r3; r3 = r4; r4 = r5; r5 = r6; r6 = r7;
            {
                int rf = (nf < 0) ? 0 : nf;
                r7 = gwb[rf * 64 + lane];
                --nf;
            }
            int jw = j >> 5, rr = j & 31;
            unsigned topmask = (rr == 31) ? 0xFFFFFFFFu : ((1u << (rr + 1)) - 1u);
            unsigned wm = (lane < jw) ? w : ((lane == jw) ? (w & topmask) : 0u);
            unsigned long long bal = __ballot(wm != 0u);
            if (bal == 0ull) {                 // no transition: row i covers 0..j
                if (lane == 0) durs[i] = j + 1;
                break;
            }
            int hl = 63 - __clzll(bal);        // highest lane (word) with a bit
            unsigned whl = (unsigned)__builtin_amdgcn_readlane((int)wm, hl);
            int jp = (hl << 5) + (31 - __clz(whl));   // largest set bit <= j
            if (lane == 0) durs[i] = j - jp + 1;
            j = jp - 1;
            if (--i < 0) break;
        }
    }
    __syncthreads();

    // ---- durations -> d_out; exclusive cumsum -> idxmap scatter fill ----
    int d[8], pre[8];
    int run = 0;
#pragma unroll
    for (int k = 0; k < 8; ++k) { d[k] = durs[lane * 8 + k]; pre[k] = run; run += d[k]; }
    int v = run;
#pragma unroll
    for (int off = 1; off < 64; off <<= 1) {
        int n = __shfl_up(v, off);
        if (lane >= off) v += n;
    }
    int base = v - run;
#pragma unroll
    for (int k = 0; k < 8; ++k) {
        int i = lane * 8 + k;
        dOut[DUR_OFF + (size_t)b * TT + i] = (float)d[k];
        int st = base + pre[k];
        for (int t2 = 0; t2 < d[k]; ++t2) idxmap[b * TM + st + t2] = i;
    }
}

// ---------------------------------------------------------------------------
// K4: length-regulate expansion. One block per output row (b, j).
// ---------------------------------------------------------------------------
__global__ __launch_bounds__(128) void k4_expand(const float* __restrict__ h_text,
                                                 const int* __restrict__ idxmap,
                                                 const int* __restrict__ mlen,
                                                 float* __restrict__ dOut) {
    int bid = blockIdx.x;
    int b = bid >> 11;
    int j = bid & (TM - 1);
    int t = threadIdx.x;
    float4* orow = (float4*)dOut + (size_t)bid * 128;
    if (j < mlen[b]) {
        int i = idxmap[bid];
        const float4* hrow = (const float4*)h_text + ((size_t)(b * TT + i)) * 128;
        orow[t] = hrow[t];
    } else {
        orow[t] = make_float4(0.f, 0.f, 0.f, 0.f);
    }
}

// ---------------------------------------------------------------------------
// K5: masked sum-MSE duration loss
// ---------------------------------------------------------------------------
__global__ __launch_bounds__(256) void k5_loss(const float* __restrict__ pred,
                                               const int* __restrict__ tlen,
                                               float* __restrict__ dOut) {
    __shared__ float rs[256];
    __shared__ int rc[256];
    int t = threadIdx.x;
    float s = 0.f;
    int c = 0;
    for (int idx = t; idx < Bn * TT; idx += 256) {
        int b = idx >> 9, i = idx & 511;
        if (i < tlen[b]) {
            float dv = dOut[DUR_OFF + idx];
            float lg = logf(fmaxf(dv, 1.0f));
            float df = pred[idx] - lg;
            s += df * df;
            c += 1;
        }
    }
    rs[t] = s; rc[t] = c;
    __syncthreads();
    for (int off = 128; off > 0; off >>= 1) {
        if (t < off) { rs[t] += rs[t + off]; rc[t] += rc[t + off]; }
        __syncthreads();
    }
    if (t == 0) dOut[LOSS_OFF] = rs[0] / (float)rc[0];
}

// ---------------------------------------------------------------------------
extern "C" void kernel_launch(void* const* d_in, const int* in_sizes, int n_in,
                              void* d_out, int out_size, void* d_ws, size_t ws_size,
                              hipStream_t stream) {
    const float* h_text = (const float*)d_in[0];
    const float* mel    = (const float*)d_in[1];
    const int*   tlen   = (const int*)d_in[2];
    const int*   mlen   = (const int*)d_in[3];
    const float* w      = (const float*)d_in[4];
    const float* bias   = (const float*)d_in[5];
    const float* pred   = (const float*)d_in[6];
    float* out = (float*)d_out;

    // workspace carve-up (~138.5 MB)
    float*    logpT  = (float*)d_ws;                              // 32*2048*512 f32 (128 MB)
    float*    hwX    = logpT + (size_t)Bn * TM * TT;              // 32*96*512 f32
    float*    wTx    = hwX + (size_t)Bn * 96 * DD;                // 96*512 f32
    unsigned* gwords = (unsigned*)(wTx + 96 * DD);                // 32*512*64 u32 (4 MB)
    int*      idxmap = (int*)(gwords + (size_t)Bn * TT * 64);     // 32*2048 i32

    k0_wtx<<<dim3(96), dim3(256), 0, stream>>>(w, bias, wTx);
    k1_hw<<<dim3(256), dim3(256), 0, stream>>>(h_text, wTx, hwX);
    k2_attn<<<dim3(64, 32), dim3(256), 0, stream>>>(hwX, mel, tlen, mlen, logpT);
    k3_dp<<<dim3(32), dim3(64), 0, stream>>>(logpT, tlen, mlen, gwords, idxmap, out);
    k4_expand<<<dim3(Bn * TM), dim3(128), 0, stream>>>(h_text, idxmap, mlen, out);
    k5_loss<<<dim3(1), dim3(256), 0, stream>>>(pred, tlen, out);
}

// Round 4
// 823.320 us; speedup vs baseline: 1.3675x; 1.1371x over previous
//
#include <hip/hip_runtime.h>
#include <math.h>

// Problem constants (fixed shapes from setup_inputs)
#define Bn 32
#define TT 512
#define TM 2048
#define DD 512
#define MMp 80
#define NEGF (-1.0e9f)

// d_out layout: [h_expanded 32*2048*512][dur_loss 1][durations 32*512], all float32
constexpr size_t LOSS_OFF = (size_t)Bn * TM * DD;          // 33554432
constexpr size_t DUR_OFF  = LOSS_OFF + 1;                  // 33554433

// ---------------------------------------------------------------------------
// K0: build wTx[96][512]: rows 0..79 = w_proj^T, row 80 = b_proj, 81..95 = 0
// ---------------------------------------------------------------------------
__global__ __launch_bounds__(256) void k0_wtx(const float* __restrict__ w,
                                              const float* __restrict__ bias,
                                              float* __restrict__ wTx) {
    int m = blockIdx.x;
    for (int d = threadIdx.x; d < DD; d += 256) {
        float v = 0.f;
        if (m < 80) v = w[d * 80 + m];
        else if (m == 80) v = bias[d];
        wTx[m * DD + d] = v;
    }
}

// ---------------------------------------------------------------------------
// K1: hwX[b][m][i] = sum_d h_text[b][i][d] * wTx[m][d]   (m<96, row80 = h.b)
// ---------------------------------------------------------------------------
__global__ __launch_bounds__(256) void k1_hw(const float* __restrict__ h_text,
                                             const float* __restrict__ wTx,
                                             float* __restrict__ hwX) {
    int bid = blockIdx.x;
    int b = bid >> 3;
    int i0 = (bid & 7) * 64;
    int t = threadIdx.x;
    int tr = t & 15, tc = t >> 4;
    __shared__ __align__(16) float Asub[64 * 68];
    __shared__ __align__(16) float Bsub[96 * 68];
    float acc[4][6];
#pragma unroll
    for (int a = 0; a < 4; ++a)
#pragma unroll
        for (int c = 0; c < 6; ++c) acc[a][c] = 0.f;

    for (int d0 = 0; d0 < DD; d0 += 64) {
        __syncthreads();
#pragma unroll
        for (int p = 0; p < 4; ++p) {
            int lin = p * 256 + t;              // 0..1023
            int r = lin >> 4, dq = lin & 15;
            *(float4*)&Asub[r * 68 + dq * 4] =
                *(const float4*)&h_text[((size_t)(b * TT + i0 + r)) * DD + d0 + dq * 4];
        }
#pragma unroll
        for (int p = 0; p < 6; ++p) {
            int lin = p * 256 + t;              // 0..1535
            int cc = lin >> 4, dq = lin & 15;
            *(float4*)&Bsub[cc * 68 + dq * 4] =
                *(const float4*)&wTx[(size_t)cc * DD + d0 + dq * 4];
        }
        __syncthreads();
#pragma unroll
        for (int dd = 0; dd < 16; ++dd) {
            float4 a[4], bb[6];
#pragma unroll
            for (int ri = 0; ri < 4; ++ri)
                a[ri] = *(const float4*)&Asub[(tr * 4 + ri) * 68 + dd * 4];
#pragma unroll
            for (int ci = 0; ci < 6; ++ci)
                bb[ci] = *(const float4*)&Bsub[(tc * 6 + ci) * 68 + dd * 4];
#pragma unroll
            for (int ri = 0; ri < 4; ++ri)
#pragma unroll
                for (int ci = 0; ci < 6; ++ci) {
                    acc[ri][ci] += a[ri].x * bb[ci].x;
                    acc[ri][ci] += a[ri].y * bb[ci].y;
                    acc[ri][ci] += a[ri].z * bb[ci].z;
                    acc[ri][ci] += a[ri].w * bb[ci].w;
                }
        }
    }
#pragma unroll
    for (int ri = 0; ri < 4; ++ri)
#pragma unroll
        for (int ci = 0; ci < 6; ++ci)
            hwX[((size_t)b * 96 + tc * 6 + ci) * DD + i0 + tr * 4 + ri] = acc[ri][ci];
}

// ---------------------------------------------------------------------------
// K2: attn + masked log_softmax over text axis, written transposed:
//   logpT[b][j][i]
// ---------------------------------------------------------------------------
__global__ __launch_bounds__(256) void k2_attn(const float* __restrict__ hwX,
                                               const float* __restrict__ mel,
                                               const int* __restrict__ tlen,
                                               const int* __restrict__ mlen,
                                               float* __restrict__ logpT) {
    const int b = blockIdx.y;
    const int ml = mlen[b];
    const int j0 = blockIdx.x * 32;
    if (j0 >= ml) return;
    const int tl = tlen[b];
    const int tid = threadIdx.x;
    const int ig = tid >> 2;   // 64 i-groups, 8 rows each
    const int jg = tid & 3;    // 4 j-groups, 8 cols each

    __shared__ __align__(16) float hwS[16 * 512];
    __shared__ __align__(16) float melS[16 * 32];
    __shared__ float red[32 * 64];
    __shared__ float colmax[32];
    __shared__ float lsum[32];

    float acc[8][8];
#pragma unroll
    for (int a = 0; a < 8; ++a)
#pragma unroll
        for (int c = 0; c < 8; ++c) acc[a][c] = 0.f;

    for (int mc = 0; mc < 80; mc += 16) {
        __syncthreads();
#pragma unroll
        for (int p = 0; p < 8; ++p) {
            int lin = p * 256 + tid;            // 0..2047 float4s
            int mm = lin >> 7, iq = lin & 127;
            *(float4*)&hwS[mm * 512 + iq * 4] =
                *(const float4*)&hwX[((size_t)b * 96 + mc + mm) * DD + iq * 4];
        }
#pragma unroll
        for (int p = 0; p < 2; ++p) {
            int lin = p * 256 + tid;            // 0..511
            int mm = lin >> 5, jj = lin & 31;
            melS[lin] = mel[((size_t)b * 80 + mc + mm) * TM + j0 + jj];
        }
        __syncthreads();
#pragma unroll
        for (int mm = 0; mm < 16; ++mm) {
            float4 a0 = *(const float4*)&hwS[mm * 512 + ig * 8];
            float4 a1 = *(const float4*)&hwS[mm * 512 + ig * 8 + 4];
            float4 b0 = *(const float4*)&melS[mm * 32 + jg * 8];
            float4 b1 = *(const float4*)&melS[mm * 32 + jg * 8 + 4];
            float av[8] = {a0.x, a0.y, a0.z, a0.w, a1.x, a1.y, a1.z, a1.w};
            float bv[8] = {b0.x, b0.y, b0.z, b0.w, b1.x, b1.y, b1.z, b1.w};
#pragma unroll
            for (int ii = 0; ii < 8; ++ii)
#pragma unroll
                for (int jj = 0; jj < 8; ++jj) acc[ii][jj] += av[ii] * bv[jj];
        }
    }
    float4 h0 = *(const float4*)&hwX[((size_t)b * 96 + 80) * DD + ig * 8];
    float4 h1 = *(const float4*)&hwX[((size_t)b * 96 + 80) * DD + ig * 8 + 4];
    float hb[8] = {h0.x, h0.y, h0.z, h0.w, h1.x, h1.y, h1.z, h1.w};
#pragma unroll
    for (int ii = 0; ii < 8; ++ii) {
        bool valid = (ig * 8 + ii) < tl;
#pragma unroll
        for (int jj = 0; jj < 8; ++jj)
            acc[ii][jj] = valid ? (acc[ii][jj] + hb[ii]) : NEGF;
    }
    __syncthreads();
#pragma unroll
    for (int jj = 0; jj < 8; ++jj) {
        float m = acc[0][jj];
#pragma unroll
        for (int ii = 1; ii < 8; ++ii) m = fmaxf(m, acc[ii][jj]);
        red[(jg * 8 + jj) * 64 + ig] = m;
    }
    __syncthreads();
    if (tid < 32) {
        float m = red[tid * 64];
        for (int g = 1; g < 64; ++g) m = fmaxf(m, red[tid * 64 + g]);
        colmax[tid] = m;
    }
    __syncthreads();
#pragma unroll
    for (int jj = 0; jj < 8; ++jj) {
        float cm = colmax[jg * 8 + jj];
        float s = 0.f;
#pragma unroll
        for (int ii = 0; ii < 8; ++ii) s += expf(acc[ii][jj] - cm);
        red[(jg * 8 + jj) * 64 + ig] = s;
    }
    __syncthreads();
    if (tid < 32) {
        float s = 0.f;
        for (int g = 0; g < 64; ++g) s += red[tid * 64 + g];
        lsum[tid] = logf(s);
    }
    __syncthreads();
#pragma unroll
    for (int jj = 0; jj < 8; ++jj) {
        int j = j0 + jg * 8 + jj;
        if (j < ml) {
            float cm = colmax[jg * 8 + jj], ls = lsum[jg * 8 + jj];
            float o[8];
#pragma unroll
            for (int ii = 0; ii < 8; ++ii) {
                int i = ig * 8 + ii;
                o[ii] = (i < tl) ? ((acc[ii][jj] - cm) - ls) : NEGF;
            }
            float* dst = &logpT[((size_t)b * TM + j) * TT + ig * 8];
            *(float4*)dst = make_float4(o[0], o[1], o[2], o[3]);
            *(float4*)(dst + 4) = make_float4(o[4], o[5], o[6], o[7]);
        }
    }
}

// ---------------------------------------------------------------------------
// K3: MAS forward DP. Key r4 restructure: the ALU phase contains ZERO DS
// instructions, so the waitcnt pass cannot inject vmcnt(0) mid-pipeline:
//   per batch: [30x ds_read_b128 -> regs][lgkmcnt(0)][30x LDS-DMA batch n+1]
//              [15 steps pure VALU, lane pass via DPP wave_shr:1][vmcnt(0)]
// DPP wave_shr:1 (ctrl 0x138) replaces __shfl_up: VALU pipe, no lgkmcnt.
// One wave per batch; lane l owns rows 8l..8l+7.
// Choice bits: gwords layout [b][i][jw]; bits for j >= ml are garbage but
// provably never read (top word masked at (ml-1)&31; lower words < ml).
// ---------------------------------------------------------------------------
#define BCOLS 15
#define NBATCH 137   // ceil(2047/15); steps j = 1..2055, cols clamped to 2047

__device__ __forceinline__ void lds_dma16(const float* g, float* l) {
    __builtin_amdgcn_global_load_lds((const __attribute__((address_space(1))) void*)g,
                                     (__attribute__((address_space(3))) void*)l,
                                     16, 0, 0);
}
#define WAITALL  asm volatile("s_waitcnt vmcnt(0)" ::: "memory")
#define WAITLGKM asm volatile("s_waitcnt lgkmcnt(0)" ::: "memory")

// lane l gets src from lane l-1; lane 0 gets `old` (bound_ctrl=false).
__device__ __forceinline__ float dpp_shr1(float old, float src) {
    return __int_as_float(__builtin_amdgcn_update_dpp(
        __float_as_int(old), __float_as_int(src), 0x138, 0xF, 0xF, false));
}

__global__ __launch_bounds__(64, 1) void k3_dp(const float* __restrict__ logpT,
                                               const int* __restrict__ tlen,
                                               const int* __restrict__ mlen,
                                               unsigned* __restrict__ gwords,
                                               int* __restrict__ idxmap,
                                               float* __restrict__ dOut) {
    const int b = blockIdx.x;
    const int lane = threadIdx.x;
    const int tl = tlen[b];
    const int ml = mlen[b];
    __shared__ __align__(16) float ring0[BCOLS * 512];
    __shared__ __align__(16) float ring1[BCOLS * 512];
    __shared__ int durs[TT];
#pragma unroll
    for (int k = 0; k < 8; ++k) durs[lane * 8 + k] = 0;

    const float* colbase = logpT + (size_t)b * TM * TT;
    unsigned* gwb = gwords + (size_t)b * TT * 64;

    float q[8];
    unsigned accb[8];
#pragma unroll
    for (int k = 0; k < 8; ++k) { q[k] = NEGF; accb[k] = 0u; }
    if (lane == 0) q[0] = colbase[0];          // logp[b][j=0][i=0]

    // ---- prologue: issue batch 0 (columns 1..15) into ring0, drain ----
    {
        const float* g0 = colbase + (size_t)512 + lane * 4;   // col 1, lane's 16B
#pragma unroll
        for (int p = 0; p < BCOLS; ++p) {
            lds_dma16(g0 + p * 512,       &ring0[p * 512]);
            lds_dma16(g0 + p * 512 + 256, &ring0[p * 512 + 256]);
        }
    }
    WAITALL;

    unsigned* gp = gwb + lane * 8 * 64;        // flush cursor (word 0)
    int jj = 1;
    for (int n = 0; n < NBATCH; ++n) {
        const float* bufc = (n & 1) ? ring1 : ring0;   // current
        float* bufn = (n & 1) ? ring0 : ring1;         // next
        // ---- phase 1: bulk LDS->reg read of batch n (no DMA outstanding) ----
        float4 ra[BCOLS], rb[BCOLS];
#pragma unroll
        for (int p = 0; p < BCOLS; ++p) {
            ra[p] = *(const float4*)&bufc[p * 512 + lane * 8];
            rb[p] = *(const float4*)&bufc[p * 512 + lane * 8 + 4];
        }
        WAITLGKM;                               // all lp data in registers
        // ---- phase 2: fire-and-forget DMA for batch n+1 ----
        if (n + 1 < NBATCH) {
            const int jb = 1 + (n + 1) * BCOLS;
#pragma unroll
            for (int p = 0; p < BCOLS; ++p) {
                int c = jb + p;
                c = (c > TM - 1) ? (TM - 1) : c;   // clamped dummy tail
                const float* g = colbase + (size_t)c * 512 + lane * 4;
                lds_dma16(g,       &bufn[p * 512]);
                lds_dma16(g + 256, &bufn[p * 512 + 256]);
            }
        }
        // ---- phase 3: 15 DP steps, pure VALU (DPP lane pass, no DS ops) ----
#pragma unroll
        for (int p = 0; p < BCOLS; ++p) {
            float lp[8] = {ra[p].x, ra[p].y, ra[p].z, ra[p].w,
                           rb[p].x, rb[p].y, rb[p].z, rb[p].w};
            float nb[8];
            nb[0] = dpp_shr1(NEGF, q[7]);      // lane 0 -> NEGF
#pragma unroll
            for (int k = 1; k < 8; ++k) nb[k] = q[k - 1];
            const unsigned m32 = 1u << (jj & 31);
#pragma unroll
            for (int k = 0; k < 8; ++k) {
                if (nb[k] > q[k]) accb[k] |= m32;        // take_diag = q_shift > q
                q[k] = lp[k] + fmaxf(q[k], nb[k]);
            }
            if ((jj & 31) == 31) {             // word complete (uniform branch)
#pragma unroll
                for (int k = 0; k < 8; ++k) { gp[k * 64] = accb[k]; accb[k] = 0u; }
                gp += 1;
            }
            ++jj;
        }
        WAITALL;                               // batch n+1 resident before swap
    }
    __threadfence();
    __syncthreads();

    // ---- wave-parallel backtrack: lane = word index within a row ----
    {
        int i = tl - 1;
        int j = ml - 1;
        unsigned r0, r1, r2, r3, r4, r5, r6, r7;   // 8-deep row shift register
        {
            int a0 = tl - 1, a1 = tl - 2, a2 = tl - 3, a3 = tl - 4;
            int a4 = tl - 5, a5 = tl - 6, a6 = tl - 7, a7 = tl - 8;
            a1 = a1 < 0 ? 0 : a1; a2 = a2 < 0 ? 0 : a2; a3 = a3 < 0 ? 0 : a3;
            a4 = a4 < 0 ? 0 : a4; a5 = a5 < 0 ? 0 : a5; a6 = a6 < 0 ? 0 : a6;
            a7 = a7 < 0 ? 0 : a7;
            r0 = gwb[a0 * 64 + lane]; r1 = gwb[a1 * 64 + lane];
            r2 = gwb[a2 * 64 + lane]; r3 = gwb[a3 * 64 + lane];
            r4 = gwb[a4 * 64 + lane]; r5 = gwb[a5 * 64 + lane];
            r6 = gwb[a6 * 64 + lane]; r7 = gwb[a7 * 64 + lane];
        }
        int nf = tl - 9;
        int guard = TT + 2;
        while (guard-- > 0) {
            unsigned w = r0;
            r0 = r1; r1 = r2; r2 = r3; r3 = r4; r4 = r5; r5 = r6; r6 = r7;
            {
                int rf = (nf < 0) ? 0 : nf;
                r7 = gwb[rf * 64 + lane];
                --nf;
            }
            int jw = j >> 5, rr = j & 31;
            unsigned topmask = (rr == 31) ? 0xFFFFFFFFu : ((1u << (rr + 1)) - 1u);
            unsigned wm = (lane < jw) ? w : ((lane == jw) ? (w & topmask) : 0u);
            unsigned long long bal = __ballot(wm != 0u);
            if (bal == 0ull) {                 // no transition: row i covers 0..j
                if (lane == 0) durs[i] = j + 1;
                break;
            }
            int hl = 63 - __clzll(bal);        // highest lane (word) with a bit
            unsigned whl = (unsigned)__builtin_amdgcn_readlane((int)wm, hl);
            int jp = (hl << 5) + (31 - __clz(whl));   // largest set bit <= j
            if (lane == 0) durs[i] = j - jp + 1;
            j = jp - 1;
            if (--i < 0) break;
        }
    }
    __syncthreads();

    // ---- durations -> d_out; exclusive cumsum -> idxmap scatter fill ----
    int d[8], pre[8];
    int run = 0;
#pragma unroll
    for (int k = 0; k < 8; ++k) { d[k] = durs[lane * 8 + k]; pre[k] = run; run += d[k]; }
    int v = run;
#pragma unroll
    for (int off = 1; off < 64; off <<= 1) {
        int n = __shfl_up(v, off);
        if (lane >= off) v += n;
    }
    int base = v - run;
#pragma unroll
    for (int k = 0; k < 8; ++k) {
        int i = lane * 8 + k;
        dOut[DUR_OFF + (size_t)b * TT + i] = (float)d[k];
        int st = base + pre[k];
        for (int t2 = 0; t2 < d[k]; ++t2) idxmap[b * TM + st + t2] = i;
    }
}

// ---------------------------------------------------------------------------
// K4: length-regulate expansion. One block per output row (b, j).
// ---------------------------------------------------------------------------
__global__ __launch_bounds__(128) void k4_expand(const float* __restrict__ h_text,
                                                 const int* __restrict__ idxmap,
                                                 const int* __restrict__ mlen,
                                                 float* __restrict__ dOut) {
    int bid = blockIdx.x;
    int b = bid >> 11;
    int j = bid & (TM - 1);
    int t = threadIdx.x;
    float4* orow = (float4*)dOut + (size_t)bid * 128;
    if (j < mlen[b]) {
        int i = idxmap[bid];
        const float4* hrow = (const float4*)h_text + ((size_t)(b * TT + i)) * 128;
        orow[t] = hrow[t];
    } else {
        orow[t] = make_float4(0.f, 0.f, 0.f, 0.f);
    }
}

// ---------------------------------------------------------------------------
// K5: masked sum-MSE duration loss
// ---------------------------------------------------------------------------
__global__ __launch_bounds__(256) void k5_loss(const float* __restrict__ pred,
                                               const int* __restrict__ tlen,
                                               float* __restrict__ dOut) {
    __shared__ float rs[256];
    __shared__ int rc[256];
    int t = threadIdx.x;
    float s = 0.f;
    int c = 0;
    for (int idx = t; idx < Bn * TT; idx += 256) {
        int b = idx >> 9, i = idx & 511;
        if (i < tlen[b]) {
            float dv = dOut[DUR_OFF + idx];
            float lg = logf(fmaxf(dv, 1.0f));
            float df = pred[idx] - lg;
            s += df * df;
            c += 1;
        }
    }
    rs[t] = s; rc[t] = c;
    __syncthreads();
    for (int off = 128; off > 0; off >>= 1) {
        if (t < off) { rs[t] += rs[t + off]; rc[t] += rc[t + off]; }
        __syncthreads();
    }
    if (t == 0) dOut[LOSS_OFF] = rs[0] / (float)rc[0];
}

// ---------------------------------------------------------------------------
extern "C" void kernel_launch(void* const* d_in, const int* in_sizes, int n_in,
                              void* d_out, int out_size, void* d_ws, size_t ws_size,
                              hipStream_t stream) {
    const float* h_text = (const float*)d_in[0];
    const float* mel    = (const float*)d_in[1];
    const int*   tlen   = (const int*)d_in[2];
    const int*   mlen   = (const int*)d_in[3];
    const float* w      = (const float*)d_in[4];
    const float* bias   = (const float*)d_in[5];
    const float* pred   = (const float*)d_in[6];
    float* out = (float*)d_out;

    // workspace carve-up (~138.5 MB)
    float*    logpT  = (float*)d_ws;                              // 32*2048*512 f32 (128 MB)
    float*    hwX    = logpT + (size_t)Bn * TM * TT;              // 32*96*512 f32
    float*    wTx    = hwX + (size_t)Bn * 96 * DD;                // 96*512 f32
    unsigned* gwords = (unsigned*)(wTx + 96 * DD);                // 32*512*64 u32 (4 MB)
    int*      idxmap = (int*)(gwords + (size_t)Bn * TT * 64);     // 32*2048 i32

    k0_wtx<<<dim3(96), dim3(256), 0, stream>>>(w, bias, wTx);
    k1_hw<<<dim3(256), dim3(256), 0, stream>>>(h_text, wTx, hwX);
    k2_attn<<<dim3(64, 32), dim3(256), 0, stream>>>(hwX, mel, tlen, mlen, logpT);
    k3_dp<<<dim3(32), dim3(64), 0, stream>>>(logpT, tlen, mlen, gwords, idxmap, out);
    k4_expand<<<dim3(Bn * TM), dim3(128), 0, stream>>>(h_text, idxmap, mlen, out);
    k5_loss<<<dim3(1), dim3(256), 0, stream>>>(pred, tlen, out);
}